// Round 3
// baseline (285.011 us; speedup 1.0000x reference)
//
#include <hip/hip_runtime.h>
#include <stdint.h>

#define NB 32
#define NL 1024
#define ND 256
// attn fp32 row = 1024 f32 = 4096 B = 2048 u16 slots. bf16 E packed in u16
// slots [0,1024); per-row fp32 partial sums (8 n-blocks) in f32 slots [512,520).
#define ROWU16 2048

typedef __attribute__((ext_vector_type(8))) __bf16 bf16x8;
typedef __attribute__((ext_vector_type(4))) float f32x4;

__device__ __forceinline__ uint16_t f2bf(float f) {
  union { float f; uint32_t u; } v; v.f = f;
  return (uint16_t)((v.u + 0x7fffu + ((v.u >> 16) & 1u)) >> 16);
}
__device__ __forceinline__ float bf2f(uint16_t h) {
  union { uint32_t u; float f; } v; v.u = ((uint32_t)h) << 16;
  return v.f;
}

#define GLD_LDS16(g, l)                                                        \
  __builtin_amdgcn_global_load_lds(                                            \
      (__attribute__((address_space(1))) void*)(g),                            \
      (__attribute__((address_space(3))) void*)(l), 16, 0, 0)

// ---------------------------------------------------------------------------
// Kernel 0: q fp32 -> Qb bf16 [b][l][d]  and  Qt bf16 [b][d][l]
// ---------------------------------------------------------------------------
__global__ __launch_bounds__(256) void convert_kernel(
    const float* __restrict__ q, uint16_t* __restrict__ qb,
    uint16_t* __restrict__ qt) {
  __shared__ uint16_t tile[64][72];
  int b = blockIdx.z;
  int l0 = blockIdx.x * 64, d0 = blockIdx.y * 64;
  int t = threadIdx.x;
  int r = t >> 4;
  int c4 = (t & 15) * 4;
  const float* qsrc = q + (size_t)b * NL * ND;
  uint16_t* qbb = qb + (size_t)b * NL * ND;
  uint16_t* qtb = qt + (size_t)b * ND * NL;
#pragma unroll
  for (int i = 0; i < 4; i++) {
    int row = r + 16 * i;
    float4 v = *(const float4*)(qsrc + (size_t)(l0 + row) * ND + d0 + c4);
    ushort4 h;
    h.x = f2bf(v.x); h.y = f2bf(v.y); h.z = f2bf(v.z); h.w = f2bf(v.w);
    *(ushort4*)(qbb + (size_t)(l0 + row) * ND + d0 + c4) = h;
    tile[row][c4 + 0] = h.x; tile[row][c4 + 1] = h.y;
    tile[row][c4 + 2] = h.z; tile[row][c4 + 3] = h.w;
  }
  __syncthreads();
#pragma unroll
  for (int i = 0; i < 4; i++) {
    int drow = r + 16 * i;
    ushort4 h;
    h.x = tile[c4 + 0][drow]; h.y = tile[c4 + 1][drow];
    h.z = tile[c4 + 2][drow]; h.w = tile[c4 + 3][drow];
    *(ushort4*)(qtb + (size_t)(d0 + drow) * NL + l0 + c4) = h;
  }
}

// ---------------------------------------------------------------------------
// Kernel 1: e = exp(S/16) (s==0 -> 0), S = Qb Qb^T.
// SINGLE-SHOT K=256: A-fragments (full K) in registers via direct global
// loads; entire 128x256 B tile staged to LDS in one burst; ONE barrier; then
// 128 back-to-back MFMAs. Writes packed bf16 E + fp32 partial row sums.
// ---------------------------------------------------------------------------
__global__ __launch_bounds__(256) void qk_kernel(
    const uint16_t* __restrict__ qb, float* __restrict__ attn_f32) {
  __shared__ alignas(16) uint16_t Bs[128 * 256];  // 64 KB, row-major, chunk-swizzled
  __shared__ float rp[128][2];
  int b = blockIdx.z;
  int m0 = blockIdx.x * 128, n0 = blockIdx.y * 128;
  const uint16_t* Q = qb + (size_t)b * NL * ND;
  int tid = threadIdx.x, lane = tid & 63, wave = tid >> 6;
  int wm = (wave & 1) * 64, wn = (wave >> 1) * 64;
  int quad = lane >> 4, l15 = lane & 15;

  // A-fragments, full K: af[tm][kg] = A[m0+wm+tm*16+l15][kg*32 + quad*8 ..+8]
  bf16x8 af[4][8];
#pragma unroll
  for (int tm = 0; tm < 4; tm++) {
    const uint16_t* ap = Q + (size_t)(m0 + wm + tm * 16 + l15) * ND + quad * 8;
#pragma unroll
    for (int kg = 0; kg < 8; kg++) af[tm][kg] = *(const bf16x8*)(ap + kg * 32);
  }

  // Stage full B tile: 4096 16B-chunks. LDS chunk (r, cl) holds global chunk
  // cl ^ (r&7) of row n0+r  -> frag reads land 2-way (free) on banks.
#pragma unroll
  for (int i = 0; i < 16; i++) {
    int ch = i * 256 + wave * 64 + lane;
    int r = ch >> 5, cl = ch & 31;
    int cg = cl ^ (r & 7);
    GLD_LDS16(Q + (size_t)(n0 + r) * ND + cg * 8,
              Bs + (size_t)(i * 256 + wave * 64) * 8);
  }
  __syncthreads();

  f32x4 acc[4][4] = {};
#pragma unroll
  for (int kg = 0; kg < 8; kg++) {
    bf16x8 bfr[4];
#pragma unroll
    for (int tn = 0; tn < 4; tn++) {
      int rb = wn + tn * 16 + l15;
      int c = (kg * 4 + quad) ^ (rb & 7);
      bfr[tn] = *(const bf16x8*)(Bs + rb * 256 + c * 8);
    }
#pragma unroll
    for (int tm = 0; tm < 4; tm++)
#pragma unroll
      for (int tn = 0; tn < 4; tn++)
        acc[tm][tn] = __builtin_amdgcn_mfma_f32_16x16x32_bf16(
            af[tm][kg], bfr[tn], acc[tm][tn], 0, 0, 0);
  }

  const float kf = 0.09016844005555f;  // log2(e)/16
  uint16_t* attn_u16 = (uint16_t*)attn_f32;
  size_t gbase = (size_t)b * NL;
#pragma unroll
  for (int tm = 0; tm < 4; tm++) {
    int rbl = wm + tm * 16 + quad * 4;
    float rsum[4] = {0.f, 0.f, 0.f, 0.f};
#pragma unroll
    for (int tn = 0; tn < 4; tn++) {
      int col = n0 + wn + tn * 16 + l15;
#pragma unroll
      for (int j = 0; j < 4; j++) {
        float s = acc[tm][tn][j];
        float e = (s == 0.0f) ? 0.0f : __builtin_amdgcn_exp2f(s * kf);
        attn_u16[(gbase + m0 + rbl + j) * ROWU16 + col] = f2bf(e);
        rsum[j] += e;
      }
    }
#pragma unroll
    for (int j = 0; j < 4; j++) {
      float v = rsum[j];
      v += __shfl_xor(v, 1, 64);
      v += __shfl_xor(v, 2, 64);
      v += __shfl_xor(v, 4, 64);
      v += __shfl_xor(v, 8, 64);
      if (l15 == 0) rp[rbl + j][wave >> 1] = v;
    }
  }
  __syncthreads();
  if (tid < 128) {
    float s = rp[tid][0] + rp[tid][1];
    attn_f32[(gbase + m0 + tid) * (size_t)NL + 512 + blockIdx.y] = s;
  }
}

// ---------------------------------------------------------------------------
// Kernel 2: out = (P @ Q) * inv_rowsum.  A = packed bf16 E, B = Qt bf16, both
// via global_load_lds. Tile 128x128, K=1024, BK=64 (16 iters, 32 KB LDS).
// ---------------------------------------------------------------------------
__global__ __launch_bounds__(256) void pv_kernel(
    const float* __restrict__ attn_f32, const uint16_t* __restrict__ qt,
    float* __restrict__ out) {
  __shared__ alignas(16) uint16_t As[128 * 64];  // 16 KB
  __shared__ alignas(16) uint16_t Bs[128 * 64];  // 16 KB
  __shared__ float inv_lds[128];
  int b = blockIdx.z;
  int m0 = blockIdx.x * 128, d0 = blockIdx.y * 128;
  const uint16_t* Ap = (const uint16_t*)attn_f32 + (size_t)b * NL * ROWU16;
  const uint16_t* Bt = qt + (size_t)b * ND * NL;
  int tid = threadIdx.x, lane = tid & 63, wave = tid >> 6;
  int wm = (wave & 1) * 64, wn = (wave >> 1) * 64;
  int quad = lane >> 4, l15 = lane & 15;
  f32x4 acc[4][4] = {};

  if (tid < 128) {
    const float* pf = attn_f32 + (size_t)(b * NL + m0 + tid) * NL + 512;
    float s = pf[0] + pf[1] + pf[2] + pf[3] + pf[4] + pf[5] + pf[6] + pf[7];
    inv_lds[tid] = (s > 0.0f) ? 1.0f / s : 0.0f;
  }

  for (int k0 = 0; k0 < NL; k0 += 64) {
    __syncthreads();
#pragma unroll
    for (int i = 0; i < 4; i++) {
      int ch = i * 256 + wave * 64 + lane;  // 1024 chunks per matrix
      int r = ch >> 3, cl = ch & 7;
      int cg = cl ^ (r & 7);
      GLD_LDS16(Ap + (size_t)(m0 + r) * ROWU16 + k0 + cg * 8,
                As + (size_t)(i * 256 + wave * 64) * 8);
      GLD_LDS16(Bt + (size_t)(d0 + r) * NL + k0 + cg * 8,
                Bs + (size_t)(i * 256 + wave * 64) * 8);
    }
    __syncthreads();
#pragma unroll
    for (int kg = 0; kg < 2; kg++) {
      bf16x8 af[4], bfr[4];
#pragma unroll
      for (int t = 0; t < 4; t++) {
        int ra = wm + t * 16 + l15;
        af[t] = *(const bf16x8*)(As + ra * 64 + (((kg * 4 + quad) ^ (ra & 7)) * 8));
        int rb = wn + t * 16 + l15;
        bfr[t] = *(const bf16x8*)(Bs + rb * 64 + (((kg * 4 + quad) ^ (rb & 7)) * 8));
      }
#pragma unroll
      for (int tm = 0; tm < 4; tm++)
#pragma unroll
        for (int tn = 0; tn < 4; tn++)
          acc[tm][tn] = __builtin_amdgcn_mfma_f32_16x16x32_bf16(
              af[tm], bfr[tn], acc[tm][tn], 0, 0, 0);
    }
  }

  float* O = out + (size_t)b * NL * ND;
#pragma unroll
  for (int tm = 0; tm < 4; tm++) {
    int rbl = wm + tm * 16 + quad * 4;
#pragma unroll
    for (int tn = 0; tn < 4; tn++) {
      int col = d0 + wn + tn * 16 + l15;
#pragma unroll
      for (int j = 0; j < 4; j++)
        O[(size_t)(m0 + rbl + j) * ND + col] = acc[tm][tn][j] * inv_lds[rbl + j];
    }
  }
}

// ---------------------------------------------------------------------------
// Kernel 3: in-place expand packed bf16 row -> normalized fp32 row.
// ---------------------------------------------------------------------------
__global__ __launch_bounds__(256) void scale_kernel(float* __restrict__ attn_f32) {
  size_t g = blockIdx.x;
  const uint16_t* u = (const uint16_t*)attn_f32 + g * ROWU16;
  float* f = attn_f32 + g * (size_t)NL;
  int t = threadIdx.x;
  ushort4 h = ((const ushort4*)u)[t];
  float s = f[512] + f[513] + f[514] + f[515] +
            f[516] + f[517] + f[518] + f[519];
  float inv = (s > 0.0f) ? 1.0f / s : 0.0f;
  __syncthreads();  // all reads of the packed row complete before overwrite
  float4 v;
  v.x = bf2f(h.x) * inv; v.y = bf2f(h.y) * inv;
  v.z = bf2f(h.z) * inv; v.w = bf2f(h.w) * inv;
  ((float4*)f)[t] = v;
}

// ---------------------------------------------------------------------------
extern "C" void kernel_launch(void* const* d_in, const int* in_sizes, int n_in,
                              void* d_out, int out_size, void* d_ws,
                              size_t ws_size, hipStream_t stream) {
  (void)in_sizes; (void)n_in; (void)out_size; (void)ws_size;
  const float* q = (const float*)d_in[0];
  float* out = (float*)d_out;
  float* attn = out + (size_t)NB * NL * ND;  // [output | attn] concat
  uint16_t* qb = (uint16_t*)d_ws;            // 16 MiB
  uint16_t* qt = qb + (size_t)NB * NL * ND;  // 16 MiB (32 MiB total)

  convert_kernel<<<dim3(16, 4, NB), 256, 0, stream>>>(q, qb, qt);
  qk_kernel<<<dim3(8, 8, NB), 256, 0, stream>>>(qb, attn);
  pv_kernel<<<dim3(8, 2, NB), 256, 0, stream>>>(attn, qt, out);
  scale_kernel<<<NB * NL, 256, 0, stream>>>(attn);
}